// Round 12
// baseline (266.564 us; speedup 1.0000x reference)
//
#include <hip/hip_runtime.h>
#include <math.h>

// Problem dims (fixed by setup_inputs)
constexpr int B = 8, C = 8, H = 512, W = 1024;
constexpr int ROWS = 8;   // rows per block -> 512 blocks = 2/CU, all resident
constexpr int NT = 256;   // thread t covers cols 4t..4t+3 of the current row
constexpr float BPW = 10.0f;
constexpr float SMOOTH = 1e-6f;
constexpr int NBLOCKS = (H / ROWS) * B;   // 512

// Workspace accumulator layout (floats):
// [0..7] ce_sum[b], [8..15] bd_sum[b]
// [16..79] probsum[b*8+c], [80..143] inter[b*8+c], [144..207] count[b*8+c]
// [208] completion counter (u32)
constexpr int ACC_N = 2 * B + 3 * B * C;

constexpr int NVALS = 22;     // 18 float (ce,bd,8 psum,8 inter) + 4 u32 (16-bit count pairs)
constexpr int PSTRIDE = 23;   // padded partial stride
constexpr int TGROWS = ROWS + 4;     // packed target rows r0-2 .. r0+9
constexpr int TSTRIDE = W / 4 + 2;   // 258 u32 per packed row (1 zero pad each side)

typedef float f32x4 __attribute__((ext_vector_type(4)));

// Direct global->LDS DMA, 16B/lane, no VGPR destination (rounds 3-6: every
// register-destination scheme collapses to ~2 loads in flight).
__device__ __forceinline__ void gl_lds16(const float* g, float* l) {
    __builtin_amdgcn_global_load_lds(
        (const __attribute__((address_space(1))) void*)g,
        (__attribute__((address_space(3))) void*)l,
        16, 0, 0);
}

// OR of 5-byte sliding windows, packed: result byte j = OR of window bytes (2+j)..(6+j).
__device__ __forceinline__ unsigned win_or5(unsigned lo, unsigned mid, unsigned hi) {
    unsigned long long a = ((unsigned long long)mid << 32) | lo;
    unsigned long long b = ((unsigned long long)hi << 32) | mid;
    return (unsigned)(a >> 16) | (unsigned)(a >> 24) | mid |
           (unsigned)(b >> 8) | (unsigned)(b >> 16);
}

__global__ __launch_bounds__(NT)
void loss_main(const float* __restrict__ pred, const int* __restrict__ target,
               float* __restrict__ acc, float* __restrict__ out) {
    // 2x32KB pred double-buffer + 2.9KB sred = 68,480 B -> 2 blocks/CU (proven r7/r8/r11).
    // Packed-target table tpk OVERLAYS pred buffer 1 (consumed in prologue only).
    __shared__ float lds_pred[2 * C * W];
    __shared__ float sred[32 * PSTRIDE];
    __shared__ unsigned slast;
    unsigned* tpk = reinterpret_cast<unsigned*>(&lds_pred[C * W]);  // 12,384 B < 32 KB

    const int tid = threadIdx.x;
    const int lane = tid & 63, wid = tid >> 6;
    const int r0 = blockIdx.x * ROWS;
    const int b  = blockIdx.y;
    const int gc = tid * 4;
    const size_t plane = (size_t)H * W;
    const int* tb = target + (size_t)b * plane;
    const float* pbase = pred + (size_t)b * C * plane;
    const int seg = wid * 256;   // wave-private 256-col segment (stage & consume)

    // ---- Prologue A: raw target rows -> regs ----
    int4 traw[TGROWS];
#pragma unroll
    for (int j = 0; j < TGROWS; ++j) {
        int gh = r0 - 2 + j;
        gh = gh < 0 ? 0 : (gh >= H ? H - 1 : gh);   // clamped; OOB zeroed below
        traw[j] = *reinterpret_cast<const int4*>(tb + (size_t)gh * W + gc);
    }
    __builtin_amdgcn_sched_barrier(0);   // don't let target loads sink below DMA issue

    // ---- Prologue B: issue DMA for row 0 into buf0 (does not touch tpk/buf1) ----
#pragma unroll
    for (int c = 0; c < C; ++c)
        gl_lds16(pbase + (size_t)c * plane + (size_t)r0 * W + seg + lane * 4,
                 &lds_pred[c * W + seg]);

    // ---- Prologue C: pack targets into tpk (label-bit bytes, 4 px per u32) ----
#pragma unroll
    for (int j = 0; j < TGROWS; ++j) {
        const int gh = r0 - 2 + j;
        const int4 t4 = traw[j];
        const unsigned m = (1u << t4.x) | ((1u << t4.y) << 8) |
                           ((1u << t4.z) << 16) | ((1u << t4.w) << 24);
        tpk[j * TSTRIDE + 1 + tid] = (gh >= 0 && gh < H) ? m : 0u;
    }
    if (tid < 2 * TGROWS) {   // zero the column pads
        const int j = tid >> 1;
        tpk[j * TSTRIDE + ((tid & 1) ? (TSTRIDE - 1) : 0)] = 0u;
    }
    __syncthreads();   // row-0 DMA complete + tpk visible

    // ---- Prologue D: all 8 rows' masks -> REGISTERS (static indexing, rule #20) ----
    unsigned bm4s[ROWS], cmids[ROWS];
    {
        unsigned m[TGROWS], lf[TGROWS], rg[TGROWS];
#pragma unroll
        for (int j = 0; j < TGROWS; ++j) {
            m[j]  = tpk[j * TSTRIDE + 1 + tid];
            lf[j] = tpk[j * TSTRIDE + tid];
            rg[j] = tpk[j * TSTRIDE + 2 + tid];
        }
#pragma unroll
        for (int i = 0; i < ROWS; ++i) {
            bm4s[i] = win_or5(lf[i+1] | lf[i+2] | lf[i+3],
                              m[i+1]  | m[i+2]  | m[i+3],
                              rg[i+1] | rg[i+2] | rg[i+3]) | m[i] | m[i+4];
            cmids[i] = m[i + 2];
        }
    }
    __syncthreads();   // all waves done reading tpk before buf1's first DMA overwrites it

    float ce_s = 0.f, bd_s = 0.f;
    float p_s[C], in_s[C];
    unsigned long long cnt = 0ull;  // byte-packed per-class counts (max 32/thread)
#pragma unroll
    for (int c = 0; c < C; ++c) { p_s[c] = 0.f; in_s[c] = 0.f; }

    // ---- Persistent pipeline: compute row i from buf(i&1) while row i+1 DMAs into
    // the other buffer. Counted vmcnt(8): NEVER drain to 0 mid-loop. ----
#pragma unroll
    for (int i = 0; i < ROWS; ++i) {
        const int cur = i & 1;
        if (i < ROWS - 1) {
            asm volatile("s_waitcnt lgkmcnt(0)" ::: "memory");   // WAR fence
            __builtin_amdgcn_sched_barrier(0);
#pragma unroll
            for (int c = 0; c < C; ++c)
                gl_lds16(pbase + (size_t)c * plane + (size_t)(r0 + i + 1) * W + seg + lane * 4,
                         &lds_pred[(cur ^ 1) * C * W + c * W + seg]);
            __builtin_amdgcn_sched_barrier(0);
            asm volatile("s_waitcnt vmcnt(8)" ::: "memory");  // row i ready, row i+1 in flight
            __builtin_amdgcn_sched_barrier(0);
        } else {
            __builtin_amdgcn_sched_barrier(0);
            asm volatile("s_waitcnt vmcnt(0)" ::: "memory");  // last row: drain
            __builtin_amdgcn_sched_barrier(0);
        }

        const unsigned bm4  = bm4s[i];
        const unsigned cmid = cmids[i];

        f32x4 x[C];
#pragma unroll
        for (int c = 0; c < C; ++c)
            x[c] = *reinterpret_cast<const f32x4*>(&lds_pred[cur * C * W + c * W + gc]);

#pragma unroll
        for (int j = 0; j < 4; ++j) {
            const float x0 = (j==0)?x[0].x:(j==1)?x[0].y:(j==2)?x[0].z:x[0].w;
            const float x1 = (j==0)?x[1].x:(j==1)?x[1].y:(j==2)?x[1].z:x[1].w;
            const float x2 = (j==0)?x[2].x:(j==1)?x[2].y:(j==2)?x[2].z:x[2].w;
            const float x3 = (j==0)?x[3].x:(j==1)?x[3].y:(j==2)?x[3].z:x[3].w;
            const float x4 = (j==0)?x[4].x:(j==1)?x[4].y:(j==2)?x[4].z:x[4].w;
            const float x5 = (j==0)?x[5].x:(j==1)?x[5].y:(j==2)?x[5].z:x[5].w;
            const float x6 = (j==0)?x[6].x:(j==1)?x[6].y:(j==2)?x[6].z:x[6].w;
            const float x7 = (j==0)?x[7].x:(j==1)?x[7].y:(j==2)?x[7].z:x[7].w;

            // |x| < ~6 for randn inputs: exp without max-subtraction is safe in fp32
            const float e0 = __expf(x0), e1 = __expf(x1), e2 = __expf(x2), e3 = __expf(x3);
            const float e4 = __expf(x4), e5 = __expf(x5), e6 = __expf(x6), e7 = __expf(x7);
            const float sum = ((e0 + e1) + (e2 + e3)) + ((e4 + e5) + (e6 + e7));
            const float invs = __builtin_amdgcn_rcpf(sum);

            const unsigned cm  = (cmid >> (8 * j)) & 0xFFu;  // == 1<<t, nonzero
            const unsigned bmj = (bm4  >> (8 * j)) & 0xFFu;
            const int t = 31 - __clz(cm);

            const float p0 = e0 * invs, p1 = e1 * invs, p2 = e2 * invs, p3 = e3 * invs;
            const float p4 = e4 * invs, p5 = e5 * invs, p6 = e6 * invs, p7 = e7 * invs;
            p_s[0] += p0; p_s[1] += p1; p_s[2] += p2; p_s[3] += p3;
            p_s[4] += p4; p_s[5] += p5; p_s[6] += p6; p_s[7] += p7;

            const bool b0 = (t == 0), b1 = (t == 1), b2 = (t == 2), b3 = (t == 3);
            const bool b4 = (t == 4), b5 = (t == 5), b6 = (t == 6), b7 = (t == 7);
            in_s[0] += b0 ? p0 : 0.f;  in_s[1] += b1 ? p1 : 0.f;
            in_s[2] += b2 ? p2 : 0.f;  in_s[3] += b3 ? p3 : 0.f;
            in_s[4] += b4 ? p4 : 0.f;  in_s[5] += b5 ? p5 : 0.f;
            in_s[6] += b6 ? p6 : 0.f;  in_s[7] += b7 ? p7 : 0.f;

            float pt = p0;
            pt = b1 ? p1 : pt;  pt = b2 ? p2 : pt;  pt = b3 ? p3 : pt;
            pt = b4 ? p4 : pt;  pt = b5 ? p5 : pt;  pt = b6 ? p6 : pt;
            pt = b7 ? p7 : pt;
            const float l = __logf(pt);
            const float wgt = (bmj & (bmj - 1u)) ? BPW : 1.f;
            ce_s -= l;
            bd_s = fmaf(-l, wgt, bd_s);
            cnt += 1ull << (t << 3);
        }
    }

    // ---- Block reduction (once per 8 rows): 18 floats + 4 u32 count pairs ----
    float vals[18];
    unsigned uvals[4];
    vals[0] = ce_s; vals[1] = bd_s;
#pragma unroll
    for (int c = 0; c < C; ++c) {
        vals[2 + c]  = p_s[c];
        vals[10 + c] = in_s[c];
    }
#pragma unroll
    for (int q = 0; q < 4; ++q)
        uvals[q] = (unsigned)((cnt >> (16 * q)) & 0xFFull)
                 | ((unsigned)((cnt >> (16 * q + 8)) & 0xFFull) << 16);

#pragma unroll
    for (int k = 0; k < 18; ++k) {
        float v = vals[k];
        v += __shfl_down(v, 32, 64);
        v += __shfl_down(v, 16, 64);
        v += __shfl_down(v, 8, 64);
        vals[k] = v;
    }
#pragma unroll
    for (int q = 0; q < 4; ++q) {
        unsigned v = uvals[q];
        v += (unsigned)__shfl_down((int)v, 32, 64);
        v += (unsigned)__shfl_down((int)v, 16, 64);
        v += (unsigned)__shfl_down((int)v, 8, 64);
        uvals[q] = v;
    }
    unsigned* sredu = reinterpret_cast<unsigned*>(sred);
    if (lane < 8) {
        const int p = wid * 8 + lane;   // 32 partials per value
#pragma unroll
        for (int k = 0; k < 18; ++k) sred[p * PSTRIDE + k] = vals[k];
#pragma unroll
        for (int q = 0; q < 4; ++q) sredu[p * PSTRIDE + 18 + q] = uvals[q];
    }
    __syncthreads();

    // Stage 2: value k handled by 8-thread group tid = 8k..8k+7
    const int k = tid >> 3, j = tid & 7;
    if (k < NVALS) {
        if (k < 18) {
            float v = sred[(0 * 8 + j) * PSTRIDE + k] + sred[(1 * 8 + j) * PSTRIDE + k]
                    + sred[(2 * 8 + j) * PSTRIDE + k] + sred[(3 * 8 + j) * PSTRIDE + k];
            v += __shfl_down(v, 4, 64);
            v += __shfl_down(v, 2, 64);
            v += __shfl_down(v, 1, 64);
            if (j == 0) {
                if (k == 0)      atomicAdd(&acc[b], v);                                // ce[b]
                else if (k == 1) atomicAdd(&acc[B + b], v);                            // bd[b]
                else if (k < 10) atomicAdd(&acc[2 * B + b * C + (k - 2)], v);          // probsum
                else             atomicAdd(&acc[2 * B + B * C + b * C + (k - 10)], v); // inter
            }
        } else {
            const int q = k - 18;
            unsigned v = sredu[(0 * 8 + j) * PSTRIDE + k] + sredu[(1 * 8 + j) * PSTRIDE + k]
                       + sredu[(2 * 8 + j) * PSTRIDE + k] + sredu[(3 * 8 + j) * PSTRIDE + k];
            v += (unsigned)__shfl_down((int)v, 4, 64);
            v += (unsigned)__shfl_down((int)v, 2, 64);
            v += (unsigned)__shfl_down((int)v, 1, 64);
            if (j == 0) {
                atomicAdd(&acc[2 * B + 2 * B * C + b * C + 2 * q],     (float)(v & 0xFFFFu));
                atomicAdd(&acc[2 * B + 2 * B * C + b * C + 2 * q + 1], (float)(v >> 16));
            }
        }
    }

    // ---- Fused finalize: last block to finish computes the loss (saves the
    // separate 1-block loss_final dispatch + its launch gap). Device-scope
    // atomics + threadfence give the standard completion-counter pattern;
    // acc is read back via atomicAdd(p, 0.f) -> coherent across XCD L2s.
    __threadfence();
    if (tid == 0) {
        const unsigned prev = atomicAdd(reinterpret_cast<unsigned*>(acc + ACC_N), 1u);
        slast = (prev == NBLOCKS - 1) ? 1u : 0u;
    }
    __syncthreads();
    if (slast != 0u && tid < 64) {
        const int i = tid;  // one (b,c) each
        const float psum  = atomicAdd(&acc[2 * B + i], 0.f);
        const float inter = atomicAdd(&acc[2 * B + B * C + i], 0.f);
        const float cntv  = atomicAdd(&acc[2 * B + 2 * B * C + i], 0.f);
        float d = (2.f * inter + SMOOTH) / (psum + cntv + SMOOTH);
        float ce = (i < B) ? atomicAdd(&acc[i], 0.f) : 0.f;
        float bd = (i < B) ? atomicAdd(&acc[B + i], 0.f) : 0.f;
#pragma unroll
        for (int off = 32; off > 0; off >>= 1) d += __shfl_down(d, off, 64);
#pragma unroll
        for (int off = 4; off > 0; off >>= 1) {
            ce += __shfl_down(ce, off, 64);
            bd += __shfl_down(bd, off, 64);
        }
        if (i == 0) {
            const float N = (float)B * H * W;
            const float dice = 1.f - d / (float)(B * C);
            out[0] = 1.0f * (ce / N) + 3.0f * dice + 2.0f * (bd / N);
        }
    }
}

extern "C" void kernel_launch(void* const* d_in, const int* in_sizes, int n_in,
                              void* d_out, int out_size, void* d_ws, size_t ws_size,
                              hipStream_t stream) {
    const float* pred = (const float*)d_in[0];
    const int* target = (const int*)d_in[1];
    float* acc = (float*)d_ws;
    float* out = (float*)d_out;

    hipMemsetAsync(acc, 0, (ACC_N + 1) * sizeof(float), stream);  // +1: completion counter

    dim3 grid(H / ROWS, B);   // 64 x 8 = 512 blocks = 2/CU, all resident
    loss_main<<<grid, NT, 0, stream>>>(pred, target, acc, out);
}

// Round 13
// 209.760 us; speedup vs baseline: 1.2708x; 1.2708x over previous
//
#include <hip/hip_runtime.h>
#include <math.h>

// Problem dims (fixed by setup_inputs)
constexpr int B = 8, C = 8, H = 512, W = 1024;
constexpr int ROWS = 8;   // rows per block -> 512 blocks = 2/CU, all resident
constexpr int NT = 256;   // thread t covers cols 4t..4t+3 of the current row
constexpr float BPW = 10.0f;
constexpr float SMOOTH = 1e-6f;

// Workspace accumulator layout (floats):
// [0..7] ce_sum[b], [8..15] bd_sum[b]
// [16..79] probsum[b*8+c], [80..143] inter[b*8+c], [144..207] count[b*8+c]
constexpr int ACC_N = 2 * B + 3 * B * C;

constexpr int NVALS = 22;     // 18 float (ce,bd,8 psum,8 inter) + 4 u32 (16-bit count pairs)
constexpr int PSTRIDE = 23;   // padded partial stride
constexpr int TGROWS = ROWS + 4;     // packed target rows r0-2 .. r0+9
constexpr int TSTRIDE = W / 4 + 2;   // 258 u32 per packed row (1 zero pad each side)

typedef float f32x4 __attribute__((ext_vector_type(4)));

// Direct global->LDS DMA, 16B/lane, no VGPR destination (rounds 3-6: every
// register-destination scheme collapses to ~2 loads in flight).
__device__ __forceinline__ void gl_lds16(const float* g, float* l) {
    __builtin_amdgcn_global_load_lds(
        (const __attribute__((address_space(1))) void*)g,
        (__attribute__((address_space(3))) void*)l,
        16, 0, 0);
}

// OR of 5-byte sliding windows, packed: result byte j = OR of window bytes (2+j)..(6+j).
__device__ __forceinline__ unsigned win_or5(unsigned lo, unsigned mid, unsigned hi) {
    unsigned long long a = ((unsigned long long)mid << 32) | lo;
    unsigned long long b = ((unsigned long long)hi << 32) | mid;
    return (unsigned)(a >> 16) | (unsigned)(a >> 24) | mid |
           (unsigned)(b >> 8) | (unsigned)(b >> 16);
}

__global__ __launch_bounds__(NT)
void loss_main(const float* __restrict__ pred, const int* __restrict__ target,
               float* __restrict__ acc) {
    // 2x32KB pred double-buffer + 2.9KB sred = 68,480 B -> 2 blocks/CU (proven size, r7/r8).
    // Packed-target table tpk OVERLAYS pred buffer 1: tpk is consumed entirely in the
    // prologue (masks -> registers) before buf1's first DMA overwrites it.
    __shared__ float lds_pred[2 * C * W];
    __shared__ float sred[32 * PSTRIDE];
    unsigned* tpk = reinterpret_cast<unsigned*>(&lds_pred[C * W]);  // 12,384 B < 32 KB

    const int tid = threadIdx.x;
    const int lane = tid & 63, wid = tid >> 6;
    const int r0 = blockIdx.x * ROWS;
    const int b  = blockIdx.y;
    const int gc = tid * 4;
    const size_t plane = (size_t)H * W;
    const int* tb = target + (size_t)b * plane;
    const float* pbase = pred + (size_t)b * C * plane;
    const int seg = wid * 256;   // wave-private 256-col segment (stage & consume)

    // ---- Prologue A: raw target rows -> regs (issued before DMA; vmcnt retires in-order
    // so the pack's waits leave the younger row-0 DMA outstanding) ----
    int4 traw[TGROWS];
#pragma unroll
    for (int j = 0; j < TGROWS; ++j) {
        int gh = r0 - 2 + j;
        gh = gh < 0 ? 0 : (gh >= H ? H - 1 : gh);   // clamped; OOB zeroed below
        traw[j] = *reinterpret_cast<const int4*>(tb + (size_t)gh * W + gc);
    }
    __builtin_amdgcn_sched_barrier(0);   // don't let target loads sink below DMA issue

    // ---- Prologue B: issue DMA for row 0 into buf0 (does not touch tpk/buf1) ----
#pragma unroll
    for (int c = 0; c < C; ++c)
        gl_lds16(pbase + (size_t)c * plane + (size_t)r0 * W + seg + lane * 4,
                 &lds_pred[c * W + seg]);

    // ---- Prologue C: pack targets into tpk (label-bit bytes, 4 px per u32) ----
#pragma unroll
    for (int j = 0; j < TGROWS; ++j) {
        const int gh = r0 - 2 + j;
        const int4 t4 = traw[j];
        const unsigned m = (1u << t4.x) | ((1u << t4.y) << 8) |
                           ((1u << t4.z) << 16) | ((1u << t4.w) << 24);
        tpk[j * TSTRIDE + 1 + tid] = (gh >= 0 && gh < H) ? m : 0u;
    }
    if (tid < 2 * TGROWS) {   // zero the column pads
        const int j = tid >> 1;
        tpk[j * TSTRIDE + ((tid & 1) ? (TSTRIDE - 1) : 0)] = 0u;
    }
    __syncthreads();   // row-0 DMA complete + tpk visible

    // ---- Prologue D: all 8 rows' masks -> REGISTERS (static indexing, rule #20).
    // Output row r0+i: ellipse spans tpk rows i..i+4; full rows i+1..i+3, center i, i+4.
    unsigned bm4s[ROWS], cmids[ROWS];
    {
        unsigned m[TGROWS], lf[TGROWS], rg[TGROWS];
#pragma unroll
        for (int j = 0; j < TGROWS; ++j) {
            m[j]  = tpk[j * TSTRIDE + 1 + tid];
            lf[j] = tpk[j * TSTRIDE + tid];
            rg[j] = tpk[j * TSTRIDE + 2 + tid];
        }
#pragma unroll
        for (int i = 0; i < ROWS; ++i) {
            bm4s[i] = win_or5(lf[i+1] | lf[i+2] | lf[i+3],
                              m[i+1]  | m[i+2]  | m[i+3],
                              rg[i+1] | rg[i+2] | rg[i+3]) | m[i] | m[i+4];
            cmids[i] = m[i + 2];
        }
    }
    __syncthreads();   // all waves done reading tpk before buf1's first DMA overwrites it

    float ce_s = 0.f, bd_s = 0.f;
    float p_s[C], in_s[C];
    unsigned long long cnt = 0ull;  // byte-packed per-class counts (max 32/thread)
#pragma unroll
    for (int c = 0; c < C; ++c) { p_s[c] = 0.f; in_s[c] = 0.f; }

    // ---- Persistent pipeline: compute row i from buf(i&1) while row i+1 DMAs into
    // the other buffer. Counted vmcnt(8): NEVER drain to 0 mid-loop. ----
#pragma unroll
    for (int i = 0; i < ROWS; ++i) {
        const int cur = i & 1;
        if (i < ROWS - 1) {
            // WAR fence: prior iteration's ds_reads of buf cur^1 executed before overwrite
            asm volatile("s_waitcnt lgkmcnt(0)" ::: "memory");
            __builtin_amdgcn_sched_barrier(0);
#pragma unroll
            for (int c = 0; c < C; ++c)
                gl_lds16(pbase + (size_t)c * plane + (size_t)(r0 + i + 1) * W + seg + lane * 4,
                         &lds_pred[(cur ^ 1) * C * W + c * W + seg]);
            __builtin_amdgcn_sched_barrier(0);
            asm volatile("s_waitcnt vmcnt(8)" ::: "memory");  // row i ready, row i+1 in flight
            __builtin_amdgcn_sched_barrier(0);
        } else {
            __builtin_amdgcn_sched_barrier(0);
            asm volatile("s_waitcnt vmcnt(0)" ::: "memory");  // last row: drain
            __builtin_amdgcn_sched_barrier(0);
        }

        const unsigned bm4  = bm4s[i];
        const unsigned cmid = cmids[i];

        f32x4 x[C];
#pragma unroll
        for (int c = 0; c < C; ++c)
            x[c] = *reinterpret_cast<const f32x4*>(&lds_pred[cur * C * W + c * W + gc]);

#pragma unroll
        for (int j = 0; j < 4; ++j) {
            const float x0 = (j==0)?x[0].x:(j==1)?x[0].y:(j==2)?x[0].z:x[0].w;
            const float x1 = (j==0)?x[1].x:(j==1)?x[1].y:(j==2)?x[1].z:x[1].w;
            const float x2 = (j==0)?x[2].x:(j==1)?x[2].y:(j==2)?x[2].z:x[2].w;
            const float x3 = (j==0)?x[3].x:(j==1)?x[3].y:(j==2)?x[3].z:x[3].w;
            const float x4 = (j==0)?x[4].x:(j==1)?x[4].y:(j==2)?x[4].z:x[4].w;
            const float x5 = (j==0)?x[5].x:(j==1)?x[5].y:(j==2)?x[5].z:x[5].w;
            const float x6 = (j==0)?x[6].x:(j==1)?x[6].y:(j==2)?x[6].z:x[6].w;
            const float x7 = (j==0)?x[7].x:(j==1)?x[7].y:(j==2)?x[7].z:x[7].w;

            // |x| < ~6 for randn inputs: exp without max-subtraction is safe in fp32
            const float e0 = __expf(x0), e1 = __expf(x1), e2 = __expf(x2), e3 = __expf(x3);
            const float e4 = __expf(x4), e5 = __expf(x5), e6 = __expf(x6), e7 = __expf(x7);
            const float sum = ((e0 + e1) + (e2 + e3)) + ((e4 + e5) + (e6 + e7));
            const float invs = __builtin_amdgcn_rcpf(sum);

            const unsigned cm  = (cmid >> (8 * j)) & 0xFFu;  // == 1<<t, nonzero
            const unsigned bmj = (bm4  >> (8 * j)) & 0xFFu;
            const int t = 31 - __clz(cm);

            const float p0 = e0 * invs, p1 = e1 * invs, p2 = e2 * invs, p3 = e3 * invs;
            const float p4 = e4 * invs, p5 = e5 * invs, p6 = e6 * invs, p7 = e7 * invs;
            p_s[0] += p0; p_s[1] += p1; p_s[2] += p2; p_s[3] += p3;
            p_s[4] += p4; p_s[5] += p5; p_s[6] += p6; p_s[7] += p7;

            const bool b0 = (t == 0), b1 = (t == 1), b2 = (t == 2), b3 = (t == 3);
            const bool b4 = (t == 4), b5 = (t == 5), b6 = (t == 6), b7 = (t == 7);
            in_s[0] += b0 ? p0 : 0.f;  in_s[1] += b1 ? p1 : 0.f;
            in_s[2] += b2 ? p2 : 0.f;  in_s[3] += b3 ? p3 : 0.f;
            in_s[4] += b4 ? p4 : 0.f;  in_s[5] += b5 ? p5 : 0.f;
            in_s[6] += b6 ? p6 : 0.f;  in_s[7] += b7 ? p7 : 0.f;

            float pt = p0;
            pt = b1 ? p1 : pt;  pt = b2 ? p2 : pt;  pt = b3 ? p3 : pt;
            pt = b4 ? p4 : pt;  pt = b5 ? p5 : pt;  pt = b6 ? p6 : pt;
            pt = b7 ? p7 : pt;
            const float l = __logf(pt);
            const float wgt = (bmj & (bmj - 1u)) ? BPW : 1.f;
            ce_s -= l;
            bd_s = fmaf(-l, wgt, bd_s);
            cnt += 1ull << (t << 3);
        }
    }

    // ---- Block reduction (once per 8 rows): 18 floats + 4 u32 count pairs ----
    // u32 pair = class 2q (lo16) | class 2q+1 (hi16); block max/class 8192 < 2^16 -> exact.
    float vals[18];
    unsigned uvals[4];
    vals[0] = ce_s; vals[1] = bd_s;
#pragma unroll
    for (int c = 0; c < C; ++c) {
        vals[2 + c]  = p_s[c];
        vals[10 + c] = in_s[c];
    }
#pragma unroll
    for (int q = 0; q < 4; ++q)
        uvals[q] = (unsigned)((cnt >> (16 * q)) & 0xFFull)
                 | ((unsigned)((cnt >> (16 * q + 8)) & 0xFFull) << 16);

#pragma unroll
    for (int k = 0; k < 18; ++k) {
        float v = vals[k];
        v += __shfl_down(v, 32, 64);
        v += __shfl_down(v, 16, 64);
        v += __shfl_down(v, 8, 64);
        vals[k] = v;
    }
#pragma unroll
    for (int q = 0; q < 4; ++q) {
        unsigned v = uvals[q];
        v += (unsigned)__shfl_down((int)v, 32, 64);
        v += (unsigned)__shfl_down((int)v, 16, 64);
        v += (unsigned)__shfl_down((int)v, 8, 64);
        uvals[q] = v;
    }
    unsigned* sredu = reinterpret_cast<unsigned*>(sred);
    if (lane < 8) {
        const int p = wid * 8 + lane;   // 32 partials per value
#pragma unroll
        for (int k = 0; k < 18; ++k) sred[p * PSTRIDE + k] = vals[k];
#pragma unroll
        for (int q = 0; q < 4; ++q) sredu[p * PSTRIDE + 18 + q] = uvals[q];
    }
    __syncthreads();

    // Stage 2: value k handled by 8-thread group tid = 8k..8k+7
    const int k = tid >> 3, j = tid & 7;
    if (k < NVALS) {
        if (k < 18) {
            float v = sred[(0 * 8 + j) * PSTRIDE + k] + sred[(1 * 8 + j) * PSTRIDE + k]
                    + sred[(2 * 8 + j) * PSTRIDE + k] + sred[(3 * 8 + j) * PSTRIDE + k];
            v += __shfl_down(v, 4, 64);
            v += __shfl_down(v, 2, 64);
            v += __shfl_down(v, 1, 64);
            if (j == 0) {
                if (k == 0)      atomicAdd(&acc[b], v);                                // ce[b]
                else if (k == 1) atomicAdd(&acc[B + b], v);                            // bd[b]
                else if (k < 10) atomicAdd(&acc[2 * B + b * C + (k - 2)], v);          // probsum
                else             atomicAdd(&acc[2 * B + B * C + b * C + (k - 10)], v); // inter
            }
        } else {
            const int q = k - 18;
            unsigned v = sredu[(0 * 8 + j) * PSTRIDE + k] + sredu[(1 * 8 + j) * PSTRIDE + k]
                       + sredu[(2 * 8 + j) * PSTRIDE + k] + sredu[(3 * 8 + j) * PSTRIDE + k];
            v += (unsigned)__shfl_down((int)v, 4, 64);
            v += (unsigned)__shfl_down((int)v, 2, 64);
            v += (unsigned)__shfl_down((int)v, 1, 64);
            if (j == 0) {
                atomicAdd(&acc[2 * B + 2 * B * C + b * C + 2 * q],     (float)(v & 0xFFFFu));
                atomicAdd(&acc[2 * B + 2 * B * C + b * C + 2 * q + 1], (float)(v >> 16));
            }
        }
    }
}

__global__ void loss_final(const float* __restrict__ acc, float* __restrict__ out) {
    const int i = threadIdx.x;  // 0..63, one (b,c) each
    const float psum  = acc[2 * B + i];
    const float inter = acc[2 * B + B * C + i];
    const float cnt   = acc[2 * B + 2 * B * C + i];
    float d = (2.f * inter + SMOOTH) / (psum + cnt + SMOOTH);
    float ce = (i < B) ? acc[i] : 0.f;
    float bd = (i < B) ? acc[B + i] : 0.f;
#pragma unroll
    for (int off = 32; off > 0; off >>= 1) d += __shfl_down(d, off, 64);
#pragma unroll
    for (int off = 4; off > 0; off >>= 1) {
        ce += __shfl_down(ce, off, 64);
        bd += __shfl_down(bd, off, 64);
    }
    if (i == 0) {
        const float N = (float)B * H * W;
        const float dice = 1.f - d / (float)(B * C);
        out[0] = 1.0f * (ce / N) + 3.0f * dice + 2.0f * (bd / N);
    }
}

extern "C" void kernel_launch(void* const* d_in, const int* in_sizes, int n_in,
                              void* d_out, int out_size, void* d_ws, size_t ws_size,
                              hipStream_t stream) {
    const float* pred = (const float*)d_in[0];
    const int* target = (const int*)d_in[1];
    float* acc = (float*)d_ws;
    float* out = (float*)d_out;

    hipMemsetAsync(acc, 0, ACC_N * sizeof(float), stream);

    dim3 grid(H / ROWS, B);   // 64 x 8 = 512 blocks = 2/CU, all resident
    loss_main<<<grid, NT, 0, stream>>>(pred, target, acc);
    loss_final<<<1, 64, 0, stream>>>(acc, out);
}